// Round 13
// baseline (95.075 us; speedup 1.0000x reference)
//
#include <hip/hip_runtime.h>
#include <hip/hip_bf16.h>
#include <math.h>

// Chamfer distance, B=8, N=M=8192, D=3, fp32.
//   C[m][n] = q_m.r_n - 0.5*||r_n||^2 via ONE v_mfma_f32_32x32x16_bf16:
//     lanes<32  (k0-7) : A={qh,1, ql,0}  B={rh,wh, rh,wh}
//     lanes>=32 (k8-15): A={qh,1, 0,0}   B={rl,wl, 0,0}
//   min_j d2 = ||q||^2_fp32 - 2*max_n C, clamped at 0.
// R19: R18 (coarse pinned phases) gave best-so-far total 94.8 but MfmaUtil
// stayed ~30: coarse {4-MFMA burst}|{32-max3 burst} phases let the 2
// symmetric waves/SIMD phase-LOCK (both burst matrix, then both fold) ->
// pipes alternate idle. m114: MFMA/VALU co-issue needs different waves in
// different phases SIMULTANEOUSLY. Fix (single variable vs R18): per-phase
// sched_group_barrier pipeline spec, CK-style fine interleave:
//     VMEM_READ x2, then 4 x { MFMA x1, VALU x8 }
// -> one wave feeds the matrix pipe every ~20 issue-cyc instead of 128-cyc
// bursts; fold VALU executes inside each MFMA's pipe shadow; matrix
// occupancy no longer relies on cross-wave anti-phasing. All compiler-known
// instrs (hazard recognizer active; fold reads the set issued one full
// phase earlier - unchanged from R18, numerically safe).
// Predicted: chamfer 42 -> 18-28us (MfmaUtil 50-75), total ~72-82us.
// FINAL pre-commit: total ~93-96 again => the 42us attractor is beyond
// HIP-level schedule surgery; stop at best-achieved.

#define BLOCK 256
#define WAVES 4
#define QPW 64        // queries per wave (two 32-row MFMA groups)

typedef short short8 __attribute__((ext_vector_type(8)));
typedef float f32x16 __attribute__((ext_vector_type(16)));

__device__ __forceinline__ unsigned int bf16hi(float f) {
    __hip_bfloat16 h = __float2bfloat16(f);
    return (unsigned int)*reinterpret_cast<unsigned short*>(&h);
}
__device__ __forceinline__ float bf16f(unsigned int u) {
    unsigned int v = u << 16;
    return *reinterpret_cast<float*>(&v);
}
__device__ __forceinline__ void cvt_split(float v, unsigned int& hi, unsigned int& lo) {
    hi = bf16hi(v);
    lo = bf16hi(v - bf16f(hi));
}

#define MFMA(a, b, c) __builtin_amdgcn_mfma_f32_32x32x16_bf16((a), (b), (c), 0, 0, 0)
#define BC8(x) __builtin_bit_cast(short8, (x))
#define SB()  __builtin_amdgcn_sched_barrier(0)
#define SGB(mask, n) __builtin_amdgcn_sched_group_barrier((mask), (n), 0)
// LLVM SchedGroupMask (m137): VALU=0x2 MFMA=0x8 VMEM_READ=0x20

// recB: pre-expanded B-fragment stream, tile t = points [32t,32t+32),
// 1024B per tile:
//   bytes [t*1024 + m*16]       = {hx,hz, hx,hz}  (hi dup, consumed by lanes<32)
//   bytes [t*1024 + 512 + m*16] = {lx,lz, 0, 0}   (lo,     consumed by lanes>=32)
// where hx = xh|(yh<<16), hz = zh|(wh<<16), w = -0.5*||p||^2.
__global__ void prep_kernel(const float* __restrict__ gts, const float* __restrict__ preds,
                            int nG, int nP, unsigned char* __restrict__ recB) {
    const int idx = blockIdx.x * blockDim.x + threadIdx.x;
    if (idx >= nG + nP) return;
    const float* src;
    unsigned char* rb;
    if (idx < nG) {
        src = gts + 3 * (size_t)idx;
        rb  = recB + (size_t)(idx >> 5) * 1024 + (size_t)(idx & 31) * 16;
    } else {
        const int j = idx - nG;
        src = preds + 3 * (size_t)j;
        rb  = recB + (size_t)nG * 32 + (size_t)(j >> 5) * 1024 + (size_t)(j & 31) * 16;
    }
    const float x = src[0], y = src[1], z = src[2];
    const float w = -0.5f * (x * x + y * y + z * z);
    unsigned int xh, xl, yh, yl, zh, zl, wh, wl;
    cvt_split(x, xh, xl); cvt_split(y, yh, yl);
    cvt_split(z, zh, zl); cvt_split(w, wh, wl);
    const unsigned int hx = xh | (yh << 16), hz = zh | (wh << 16);
    const unsigned int lx = xl | (yl << 16), lz = zl | (wl << 16);
    *(uint4*)(rb)       = make_uint4(hx, hz, hx, hz);
    *(uint4*)(rb + 512) = make_uint4(lx, lz, 0u, 0u);
}

__global__ void __launch_bounds__(BLOCK, 2)
chamfer_kernel(const float* __restrict__ gts, const float* __restrict__ preds,
               const uint4* __restrict__ recB, int N, int M, int B,
               float invx, float invy, float* __restrict__ out) {
    const int z = blockIdx.y;
    const bool dirX = (z < B);
    const int b = dirX ? z : z - B;
    const int NQ = dirX ? N : M;
    const int NR = dirX ? M : N;
    const float* Q = (dirX ? gts : preds) + (size_t)b * NQ * 3;
    const float inv = dirX ? invx : invy;
    const uint4* Rb4 = recB + (dirX ? (size_t)B * N * 2 : 0) + (size_t)b * NR * 2;

    const int tid = threadIdx.x;
    const int lane = tid & 63;
    const int wave = tid >> 6;
    const int m = lane & 31;
    const bool isHi = lane < 32;
    const unsigned int loMask = isHi ? 0xFFFFFFFFu : 0u;
    const int qBase = (blockIdx.x * WAVES + wave) * QPW;

    // ---- A fragments from raw queries (once; negligible). Exact fp32 norms.
    float n2q0, n2q1;
    short8 A0, A1;
    {
        const float* qp = Q + 3 * (size_t)(qBase + m);
        const float x = qp[0], y = qp[1], zz = qp[2];
        n2q0 = x * x + y * y + zz * zz;
        unsigned int xh, xl, yh, yl, zh, zl;
        cvt_split(x, xh, xl); cvt_split(y, yh, yl); cvt_split(zz, zh, zl);
        uint4 a = make_uint4(xh | (yh << 16), zh | 0x3F800000u,
                             (xl | (yl << 16)) & loMask, zl & loMask);
        A0 = BC8(a);
    }
    {
        const float* qp = Q + 3 * (size_t)(qBase + 32 + m);
        const float x = qp[0], y = qp[1], zz = qp[2];
        n2q1 = x * x + y * y + zz * zz;
        unsigned int xh, xl, yh, yl, zh, zl;
        cvt_split(x, xh, xl); cvt_split(y, yh, yl); cvt_split(zz, zh, zl);
        uint4 a = make_uint4(xh | (yh << 16), zh | 0x3F800000u,
                             (xl | (yl << 16)) & loMask, zl & loMask);
        A1 = BC8(a);
    }

    f32x16 k0, k1, zc;
    #pragma unroll
    for (int r = 0; r < 16; ++r) { k0[r] = -INFINITY; k1[r] = -INFINITY; zc[r] = 0.0f; }

    // 2-deep ping-pong MFMA tuple sets (kept live by per-phase SB fences).
    f32x16 cA0, cA1, cA2, cA3, cB0, cB1, cB2, cB3;

    // Issue one group (2 ref tiles ba,bb x A0,A1 = 4 MFMA) into set P.
#define MF4(P, ba, bb) do {                                                  \
        P##0 = MFMA(A0, BC8(ba), zc);                                        \
        P##1 = MFMA(A0, BC8(bb), zc);                                        \
        P##2 = MFMA(A1, BC8(ba), zc);                                        \
        P##3 = MFMA(A1, BC8(bb), zc);                                        \
    } while (0)
    // Fold set P into running maxima (32 v_max3 via maxnum fusion).
#define FOLD(P) do {                                                         \
        _Pragma("unroll")                                                    \
        for (int r = 0; r < 16; ++r)                                         \
            k0[r] = fmaxf(fmaxf(P##0[r], P##1[r]), k0[r]);                   \
        _Pragma("unroll")                                                    \
        for (int r = 0; r < 16; ++r)                                         \
            k1[r] = fmaxf(fmaxf(P##2[r], P##3[r]), k1[r]);                   \
    } while (0)
    // CK-style per-phase pipeline spec: 2 loads first, then 1 MFMA : 8 VALU
    // fine interleave (4x). Emitted at phase end; SB delimits the region.
#define PIPE() do {                                                          \
        SGB(0x20, 2);                                                        \
        SGB(0x8, 1); SGB(0x2, 8);                                            \
        SGB(0x8, 1); SGB(0x2, 8);                                            \
        SGB(0x8, 1); SGB(0x2, 8);                                            \
        SGB(0x8, 1); SGB(0x2, 8);                                            \
        SB();                                                                \
    } while (0)

    // Lane l reads its 16B fragment of tile t at Rb4[t*64 + lane].
    // Body = 8 tiles (4 groups). Self-overwriting buffer X0..X7: each pair
    // reloaded with next body's tiles right after its last use.
    const int NT = NR / 32;                         // 256 tiles, 32 bodies
    const uint4* p = Rb4 + lane;
    uint4 X0 = p[0],   X1 = p[64],  X2 = p[128], X3 = p[192];
    uint4 X4 = p[256], X5 = p[320], X6 = p[384], X7 = p[448];
    MF4(cA, X0, X1);                                // group 0 in flight
    SB();

    #pragma unroll 1
    for (int bdy = 0; bdy < NT / 8; ++bdy) {
        // entry invariant: cA = group a (first group of this body), issued
        X0 = p[512]; X1 = p[576];                   // next body's tiles 0,1
        MF4(cB, X2, X3);
        FOLD(cA);                                   // reads prev-phase set
        PIPE();
        X2 = p[640]; X3 = p[704];
        MF4(cA, X4, X5);
        FOLD(cB);
        PIPE();
        X4 = p[768]; X5 = p[832];
        MF4(cB, X6, X7);
        FOLD(cA);
        PIPE();
        X6 = p[896]; X7 = p[960];
        MF4(cA, X0, X1);                            // next body's first group
        FOLD(cB);
        PIPE();
        p += 512;
    }
    // Last body issued a garbage group (tiles NT..NT+1 from the ~8KB
    // over-read past this direction's chunk - still inside recB/ws, never
    // folded; NaNs cannot propagate).
#undef MF4
#undef FOLD
#undef PIPE

    // ---- epilogue: wave-private LDS transpose, then row max-reduce.
    // C/D layout: col=lane&31, row=(r&3)+8*(r>>2)+4*(lane>>5).
    __shared__ float sT[WAVES][64][36];             // +4 pad: conflict-free
    #pragma unroll
    for (int r = 0; r < 16; ++r) {
        const int row = (r & 3) + 8 * (r >> 2) + 4 * (lane >> 5);
        sT[wave][row][m]      = k0[r];              // group 0 -> rows 0..31
        sT[wave][32 + row][m] = k1[r];              // group 1 -> rows 32..63
    }
    const float4* rowp = (const float4*)&sT[wave][lane][0];
    float4 m01 = rowp[0];
    #pragma unroll
    for (int kk = 1; kk < 8; ++kk) {
        const float4 t = rowp[kk];
        m01.x = fmaxf(m01.x, t.x); m01.y = fmaxf(m01.y, t.y);
        m01.z = fmaxf(m01.z, t.z); m01.w = fmaxf(m01.w, t.w);
    }
    const float cmax = fmaxf(fmaxf(m01.x, m01.y), fmaxf(m01.z, m01.w));

    // lane owns query qBase+lane; exact fp32 norm from the prologue.
    const float q2own = isHi ? n2q0 : n2q1;
    float v = fmaxf(q2own - 2.0f * cmax, 0.0f) * inv;

    // block reduction -> one atomicAdd (out zeroed by harness each iter)
    #pragma unroll
    for (int off = 32; off; off >>= 1) v += __shfl_xor(v, off);
    __shared__ float waveSums[WAVES];
    if (lane == 0) waveSums[wave] = v;
    __syncthreads();
    if (tid == 0) {
        float s = 0.0f;
        #pragma unroll
        for (int w = 0; w < WAVES; ++w) s += waveSums[w];
        atomicAdd(out, s);
    }
}

extern "C" void kernel_launch(void* const* d_in, const int* in_sizes, int n_in,
                              void* d_out, int out_size, void* d_ws, size_t ws_size,
                              hipStream_t stream) {
    const float* gts   = (const float*)d_in[0];   // [B, N, 3]
    const float* preds = (const float*)d_in[1];   // [B, M, 3]
    float* out = (float*)d_out;

    const int B = 8;
    const int N = in_sizes[0] / (B * 3);
    const int M = in_sizes[1] / (B * 3);
    const int nG = B * N, nP = B * M;

    unsigned char* recB = (unsigned char*)d_ws;   // (nG+nP)*32B = 4MB (+8KB
                                                  //  over-read slack in ws)
    prep_kernel<<<(nG + nP + BLOCK - 1) / BLOCK, BLOCK, 0, stream>>>(
        gts, preds, nG, nP, recB);

    dim3 grid(N / (WAVES * QPW), 2 * B);          // 32 x 16 = 512 = 2/CU
    chamfer_kernel<<<grid, BLOCK, 0, stream>>>(
        gts, preds, (const uint4*)recB, N, M, B,
        1.0f / (float)nG, 1.0f / (float)nP, out);
}

// Round 14
// 93.469 us; speedup vs baseline: 1.0172x; 1.0172x over previous
//
#include <hip/hip_runtime.h>
#include <hip/hip_bf16.h>
#include <math.h>

// Chamfer distance, B=8, N=M=8192, D=3, fp32.
//   C[m][n] = q_m.r_n - 0.5*||r_n||^2 via ONE v_mfma_f32_32x32x16_bf16:
//     lanes<32  (k0-7) : A={qh,1, ql,0}  B={rh,wh, rh,wh}
//     lanes>=32 (k8-15): A={qh,1, 0,0}   B={rl,wl, 0,0}
//   min_j d2 = ||q||^2_fp32 - 2*max_n C, clamped at 0.
// R20: accounting fix - fmaxf(fmaxf) does NOT fuse to v_max3 without
// -ffast-math (maxnum->max3 needs nnan). Measured 65 VALU/group = 64 v_max
// + addr confirms it: fold VALU demand EQUALED MFMA demand all along, and
// R19's SGB spec (32 VALU) covered only half the real VALU. This round =
// R18 exactly (best total 94.8) with ONE change: fold = 32 x inline-asm
// v_max3_f32. Safety: R15's max3 failure was the HAZARD (no pins, read
// 4-8cyc after MFMA; MAI hazard recognizer ignores INLINEASM uses), not
// NaN (all values finite by construction). Here every fold reads the set
// issued a full SB-phase earlier (>=4 MFMA + 2 load issues) PLUS the
// R0/R10-validated data-tied s_nop 7x2 fence -> read-age >= validated
// margin. Predicted: VALU/group 68->38, VALUBusy 33->18%, chamfer 42->
// 31-36us, total ~87-90. FINAL pre-commit: total >=93 (VALU halved but
// wall unmoved => stall absorbs all) -> declare best-achieved, stop.

#define BLOCK 256
#define WAVES 4
#define QPW 64        // queries per wave (two 32-row MFMA groups)

typedef short short8 __attribute__((ext_vector_type(8)));
typedef float f32x16 __attribute__((ext_vector_type(16)));

__device__ __forceinline__ unsigned int bf16hi(float f) {
    __hip_bfloat16 h = __float2bfloat16(f);
    return (unsigned int)*reinterpret_cast<unsigned short*>(&h);
}
__device__ __forceinline__ float bf16f(unsigned int u) {
    unsigned int v = u << 16;
    return *reinterpret_cast<float*>(&v);
}
__device__ __forceinline__ void cvt_split(float v, unsigned int& hi, unsigned int& lo) {
    hi = bf16hi(v);
    lo = bf16hi(v - bf16f(hi));
}

#define MFMA(a, b, c) __builtin_amdgcn_mfma_f32_32x32x16_bf16((a), (b), (c), 0, 0, 0)
#define BC8(x) __builtin_bit_cast(short8, (x))
#define SB()  __builtin_amdgcn_sched_barrier(0)

// Single-instruction 3-input max. Non-volatile; numerically exact for
// finite inputs (all our values are finite by construction). Only used on
// MFMA dests whose read-age is pinned >= hazard margin (SB phase + fence).
__device__ __forceinline__ float max3f(float a, float b, float c) {
    float d;
    asm("v_max3_f32 %0, %1, %2, %3" : "=v"(d) : "v"(a), "v"(b), "v"(c));
    return d;
}
// R0/R10-validated data-tied hazard fence: 16 wait cycles tied to the set
// about to be folded (inline-asm reads bypass the MAI hazard recognizer).
__device__ __forceinline__ void mfma_fence4(f32x16& a, f32x16& b, f32x16& c, f32x16& d) {
    asm volatile("s_nop 7\n\ts_nop 7" : "+v"(a), "+v"(b), "+v"(c), "+v"(d));
}

// recB: pre-expanded B-fragment stream, tile t = points [32t,32t+32),
// 1024B per tile:
//   bytes [t*1024 + m*16]       = {hx,hz, hx,hz}  (hi dup, consumed by lanes<32)
//   bytes [t*1024 + 512 + m*16] = {lx,lz, 0, 0}   (lo,     consumed by lanes>=32)
// where hx = xh|(yh<<16), hz = zh|(wh<<16), w = -0.5*||p||^2.
__global__ void prep_kernel(const float* __restrict__ gts, const float* __restrict__ preds,
                            int nG, int nP, unsigned char* __restrict__ recB) {
    const int idx = blockIdx.x * blockDim.x + threadIdx.x;
    if (idx >= nG + nP) return;
    const float* src;
    unsigned char* rb;
    if (idx < nG) {
        src = gts + 3 * (size_t)idx;
        rb  = recB + (size_t)(idx >> 5) * 1024 + (size_t)(idx & 31) * 16;
    } else {
        const int j = idx - nG;
        src = preds + 3 * (size_t)j;
        rb  = recB + (size_t)nG * 32 + (size_t)(j >> 5) * 1024 + (size_t)(j & 31) * 16;
    }
    const float x = src[0], y = src[1], z = src[2];
    const float w = -0.5f * (x * x + y * y + z * z);
    unsigned int xh, xl, yh, yl, zh, zl, wh, wl;
    cvt_split(x, xh, xl); cvt_split(y, yh, yl);
    cvt_split(z, zh, zl); cvt_split(w, wh, wl);
    const unsigned int hx = xh | (yh << 16), hz = zh | (wh << 16);
    const unsigned int lx = xl | (yl << 16), lz = zl | (wl << 16);
    *(uint4*)(rb)       = make_uint4(hx, hz, hx, hz);
    *(uint4*)(rb + 512) = make_uint4(lx, lz, 0u, 0u);
}

__global__ void __launch_bounds__(BLOCK, 2)
chamfer_kernel(const float* __restrict__ gts, const float* __restrict__ preds,
               const uint4* __restrict__ recB, int N, int M, int B,
               float invx, float invy, float* __restrict__ out) {
    const int z = blockIdx.y;
    const bool dirX = (z < B);
    const int b = dirX ? z : z - B;
    const int NQ = dirX ? N : M;
    const int NR = dirX ? M : N;
    const float* Q = (dirX ? gts : preds) + (size_t)b * NQ * 3;
    const float inv = dirX ? invx : invy;
    const uint4* Rb4 = recB + (dirX ? (size_t)B * N * 2 : 0) + (size_t)b * NR * 2;

    const int tid = threadIdx.x;
    const int lane = tid & 63;
    const int wave = tid >> 6;
    const int m = lane & 31;
    const bool isHi = lane < 32;
    const unsigned int loMask = isHi ? 0xFFFFFFFFu : 0u;
    const int qBase = (blockIdx.x * WAVES + wave) * QPW;

    // ---- A fragments from raw queries (once; negligible). Exact fp32 norms.
    float n2q0, n2q1;
    short8 A0, A1;
    {
        const float* qp = Q + 3 * (size_t)(qBase + m);
        const float x = qp[0], y = qp[1], zz = qp[2];
        n2q0 = x * x + y * y + zz * zz;
        unsigned int xh, xl, yh, yl, zh, zl;
        cvt_split(x, xh, xl); cvt_split(y, yh, yl); cvt_split(zz, zh, zl);
        uint4 a = make_uint4(xh | (yh << 16), zh | 0x3F800000u,
                             (xl | (yl << 16)) & loMask, zl & loMask);
        A0 = BC8(a);
    }
    {
        const float* qp = Q + 3 * (size_t)(qBase + 32 + m);
        const float x = qp[0], y = qp[1], zz = qp[2];
        n2q1 = x * x + y * y + zz * zz;
        unsigned int xh, xl, yh, yl, zh, zl;
        cvt_split(x, xh, xl); cvt_split(y, yh, yl); cvt_split(zz, zh, zl);
        uint4 a = make_uint4(xh | (yh << 16), zh | 0x3F800000u,
                             (xl | (yl << 16)) & loMask, zl & loMask);
        A1 = BC8(a);
    }

    f32x16 k0, k1, zc;
    #pragma unroll
    for (int r = 0; r < 16; ++r) { k0[r] = -INFINITY; k1[r] = -INFINITY; zc[r] = 0.0f; }

    // 2-deep ping-pong MFMA tuple sets (kept live by the SB fences).
    f32x16 cA0, cA1, cA2, cA3, cB0, cB1, cB2, cB3;

    // Issue one group (2 ref tiles ba,bb x A0,A1 = 4 MFMA) into set P.
#define MF4(P, ba, bb) do {                                                  \
        P##0 = MFMA(A0, BC8(ba), zc);                                        \
        P##1 = MFMA(A0, BC8(bb), zc);                                        \
        P##2 = MFMA(A1, BC8(ba), zc);                                        \
        P##3 = MFMA(A1, BC8(bb), zc);                                        \
    } while (0)
    // Fold set P into running maxima: fence (hazard margin) + 32 v_max3.
#define FOLD(P) do {                                                         \
        mfma_fence4(P##0, P##1, P##2, P##3);                                 \
        _Pragma("unroll")                                                    \
        for (int r = 0; r < 16; ++r)                                         \
            k0[r] = max3f(P##0[r], P##1[r], k0[r]);                          \
        _Pragma("unroll")                                                    \
        for (int r = 0; r < 16; ++r)                                         \
            k1[r] = max3f(P##2[r], P##3[r], k1[r]);                          \
    } while (0)

    // Lane l reads its 16B fragment of tile t at Rb4[t*64 + lane].
    // Body = 8 tiles (4 groups). Self-overwriting buffer X0..X7: each pair
    // reloaded with next body's tiles right after its last use.
    const int NT = NR / 32;                         // 256 tiles, 32 bodies
    const uint4* p = Rb4 + lane;
    uint4 X0 = p[0],   X1 = p[64],  X2 = p[128], X3 = p[192];
    uint4 X4 = p[256], X5 = p[320], X6 = p[384], X7 = p[448];
    MF4(cA, X0, X1);                                // group 0 in flight
    SB();

    #pragma unroll 1
    for (int bdy = 0; bdy < NT / 8; ++bdy) {
        // entry invariant: cA = group a (first group of this body), issued
        X0 = p[512]; X1 = p[576];                   // next body's tiles 0,1
        MF4(cB, X2, X3);
        SB();                                       // pin: fold can't move up
        FOLD(cA);                                   // reads prev-phase set
        SB();
        X2 = p[640]; X3 = p[704];
        MF4(cA, X4, X5);
        SB();
        FOLD(cB);
        SB();
        X4 = p[768]; X5 = p[832];
        MF4(cB, X6, X7);
        SB();
        FOLD(cA);
        SB();
        X6 = p[896]; X7 = p[960];
        MF4(cA, X0, X1);                            // next body's first group
        SB();
        FOLD(cB);
        SB();
        p += 512;
    }
    // Last body issued a garbage group (tiles NT..NT+1 from the ~8KB
    // over-read past this direction's chunk - still inside recB/ws, never
    // folded; NaNs cannot propagate).
#undef MF4
#undef FOLD

    // ---- epilogue: wave-private LDS transpose, then row max-reduce.
    // C/D layout: col=lane&31, row=(r&3)+8*(r>>2)+4*(lane>>5).
    __shared__ float sT[WAVES][64][36];             // +4 pad: conflict-free
    #pragma unroll
    for (int r = 0; r < 16; ++r) {
        const int row = (r & 3) + 8 * (r >> 2) + 4 * (lane >> 5);
        sT[wave][row][m]      = k0[r];              // group 0 -> rows 0..31
        sT[wave][32 + row][m] = k1[r];              // group 1 -> rows 32..63
    }
    const float4* rowp = (const float4*)&sT[wave][lane][0];
    float4 m01 = rowp[0];
    #pragma unroll
    for (int kk = 1; kk < 8; ++kk) {
        const float4 t = rowp[kk];
        m01.x = fmaxf(m01.x, t.x); m01.y = fmaxf(m01.y, t.y);
        m01.z = fmaxf(m01.z, t.z); m01.w = fmaxf(m01.w, t.w);
    }
    const float cmax = fmaxf(fmaxf(m01.x, m01.y), fmaxf(m01.z, m01.w));

    // lane owns query qBase+lane; exact fp32 norm from the prologue.
    const float q2own = isHi ? n2q0 : n2q1;
    float v = fmaxf(q2own - 2.0f * cmax, 0.0f) * inv;

    // block reduction -> one atomicAdd (out zeroed by harness each iter)
    #pragma unroll
    for (int off = 32; off; off >>= 1) v += __shfl_xor(v, off);
    __shared__ float waveSums[WAVES];
    if (lane == 0) waveSums[wave] = v;
    __syncthreads();
    if (tid == 0) {
        float s = 0.0f;
        #pragma unroll
        for (int w = 0; w < WAVES; ++w) s += waveSums[w];
        atomicAdd(out, s);
    }
}

extern "C" void kernel_launch(void* const* d_in, const int* in_sizes, int n_in,
                              void* d_out, int out_size, void* d_ws, size_t ws_size,
                              hipStream_t stream) {
    const float* gts   = (const float*)d_in[0];   // [B, N, 3]
    const float* preds = (const float*)d_in[1];   // [B, M, 3]
    float* out = (float*)d_out;

    const int B = 8;
    const int N = in_sizes[0] / (B * 3);
    const int M = in_sizes[1] / (B * 3);
    const int nG = B * N, nP = B * M;

    unsigned char* recB = (unsigned char*)d_ws;   // (nG+nP)*32B = 4MB (+8KB
                                                  //  over-read slack in ws)
    prep_kernel<<<(nG + nP + BLOCK - 1) / BLOCK, BLOCK, 0, stream>>>(
        gts, preds, nG, nP, recB);

    dim3 grid(N / (WAVES * QPW), 2 * B);          // 32 x 16 = 512 = 2/CU
    chamfer_kernel<<<grid, BLOCK, 0, stream>>>(
        gts, preds, (const uint4*)recB, N, M, B,
        1.0f / (float)nG, 1.0f / (float)nP, out);
}